// Round 11
// baseline (62.077 us; speedup 1.0000x reference)
//
#include <hip/hip_runtime.h>
#include <hip/hip_fp16.h>
#include <stdint.h>

#define BATCH 128
#define CIN   64
#define NFLOW 16
#define COUT  256
#define HH    20
#define WW    20
#define NPIX  400
#define KTOT  1024
#define PT    100         // pixel tile (5 image rows)
#define NPT   4           // tiles per batch -> 512 blocks = exactly 2/CU
#define NTH   512         // 8 waves, each owns 32 out-rows x all 7 N-frags
#define NFR   7           // N-frags per tile (112 cols cover 100 pixels)
#define FLR   112         // fl rows (NFR*16)

typedef __attribute__((ext_vector_type(8))) short sh8;   // MFMA A/B frag (8 f16)
typedef __attribute__((ext_vector_type(4))) float f4;    // MFMA C/D frag

// ---- prep: W fp32 [256][1024] -> f16 MFMA-frag layout over permuted k' ----
// k' = kc*64 + fi*8 + ci ; kc = fb*8 + cb ; f = fb*8+fi, c = cb*8+ci, k = c*16+f.
// Frag layout: Wf[((kc16*16 + mf)*64 + h*16 + lr)*8 + j], k' = kc16*32 + h*8 + j,
// row m = mf*16 + lr.
__global__ void prep_w(const float* __restrict__ wg, __half* __restrict__ Wf) {
    int gid = blockIdx.x * 256 + threadIdx.x;   // [0, 32768)
    int j8  = gid & 127;          // k'-octet 0..127
    int row = gid >> 7;           // 0..255
    int kc16 = j8 >> 2;
    int h    = j8 & 3;
    __half* dst = Wf + ((size_t)(kc16 * 16 + (row >> 4)) * 64 + h * 16 + (row & 15)) * 8;
    #pragma unroll
    for (int j = 0; j < 8; ++j) {
        int kp = j8 * 8 + j;                  // k' in [0,1024)
        int kc = kp >> 6;
        int l  = kp & 63;
        int f  = (kc >> 3) * 8 + (l >> 3);
        int c  = (kc & 7) * 8 + (l & 7);
        dst[j] = __float2half(wg[(size_t)row * KTOT + c * NFLOW + f]);
    }
}

// ---- prep: x fp32 [b][c][pix] -> xt f16 chunk-planar [b][cb][pix][ci8] ----
// One chunk-plane = 400 cells x 16 B contiguous; L1/L2-resident during main.
__global__ void prep_x(const float* __restrict__ xg, __half* __restrict__ xt) {
    int gid = blockIdx.x * 256 + threadIdx.x;   // cell id [0, 409600)
    int b   = gid / (8 * NPIX);
    int r   = gid - b * (8 * NPIX);             // cb*400 + pix
    int cb  = r / NPIX;
    int pix = r - cb * NPIX;
    const float* src = xg + (size_t)b * (CIN * NPIX) + (size_t)(cb * 8) * NPIX + pix;
    __half2 h0 = __floats2half2_rn(src[0 * NPIX], src[1 * NPIX]);
    __half2 h1 = __floats2half2_rn(src[2 * NPIX], src[3 * NPIX]);
    __half2 h2 = __floats2half2_rn(src[4 * NPIX], src[5 * NPIX]);
    __half2 h3 = __floats2half2_rn(src[6 * NPIX], src[7 * NPIX]);
    uint4 pk;
    pk.x = __builtin_bit_cast(uint32_t, h0);
    pk.y = __builtin_bit_cast(uint32_t, h1);
    pk.z = __builtin_bit_cast(uint32_t, h2);
    pk.w = __builtin_bit_cast(uint32_t, h3);
    *(uint4*)&xt[(size_t)gid * 8] = pk;         // contiguous 16B cells across threads
}

__global__ __launch_bounds__(NTH, 4) void flow_main(
    const __half* __restrict__ xt, const __half* __restrict__ Wf,
    const float* __restrict__ flowg, const float* __restrict__ biasg,
    float* __restrict__ outg)
{
    // fl: B-tile dbuf, row stride 64 f16 = 128 B, XOR-swizzled 16B cells.
    // ONLY LDS use -- gathers come straight from L1/L2-resident xt.
    __shared__ __align__(16) __half fl[2][FLR * 64];      // 28672 B total

    const int bid0 = blockIdx.x;
    const int bid  = (bid0 & 7) * 64 + (bid0 >> 3);       // XCD swizzle; the 4 blocks
    const int b  = bid >> 2;                              // of one image share an XCD
    const int pt = bid & 3;
    const int p0 = pt * PT;

    const int tid  = threadIdx.x;
    const int wv   = tid >> 6;        // wave owns out-rows [wv*32, wv*32+32), flow fi=wv
    const int lane = tid & 63;
    const int lr   = lane & 15;
    const int hq   = lane >> 4;       // k-slice quarter 0..3

    const char* xtb = (const char*)(xt + (size_t)b * (8 * NPIX * 8));  // image base

    // ---- warp tables: wave wv handles flow fi=wv, pixels p = it*64 + lane ----
    __half2 w2_[2][4];
    int     pb_[2][4];     // corner cell byte offset within a chunk plane (r * 16)
    int     fo_[2];        // fl byte offset = p*128 + ((wv ^ (p&7))<<4)

    auto build_tables = [&](int fb) {
        #pragma unroll
        for (int it = 0; it < 2; ++it) {
            if (it == 0 || lane < PT - 64) {
                int p  = it * 64 + lane;       // [0,100)
                int f  = fb * 8 + wv;
                int gp = p0 + p;
                int i = gp / WW;
                int j = gp - i * WW;
                float fx = flowg[((f * HH + i) * WW + j) * 2 + 0];
                float fy = flowg[((f * HH + i) * WW + j) * 2 + 1];
                float ax = (float)i + fx;
                float ay = (float)j + fy;
                float bxf = floorf(ax), byf = floorf(ay);
                float s = ax - bxf, t = ay - byf;
                int ibx = (int)bxf, iby = (int)byf;
                float w00 = (1.f - s) * (1.f - t);
                float w01 = s * (1.f - t);
                float w10 = s * (1.f - t);        // replicate reference's weight bug
                float w11 = s * t;
                int cx0 = min(max(ibx, 0), HH);
                int cx1 = min(max(ibx + 1, 0), HH);
                int cy0 = min(max(iby, 0), WW);
                int cy1 = min(max(iby + 1, 0), WW);
                int v0 = (cx0 < HH) & (cy0 < WW);
                int v1 = (cx1 < HH) & (cy0 < WW);
                int v2 = (cx0 < HH) & (cy1 < WW);
                int v3 = (cx1 < HH) & (cy1 < WW);
                w2_[it][0] = __half2half2(__float2half(v0 ? w00 : 0.f));
                w2_[it][1] = __half2half2(__float2half(v1 ? w01 : 0.f));
                w2_[it][2] = __half2half2(__float2half(v2 ? w10 : 0.f));
                w2_[it][3] = __half2half2(__float2half(v3 ? w11 : 0.f));
                pb_[it][0] = (v0 ? (cx0 * WW + cy0) : 0) * 16;
                pb_[it][1] = (v1 ? (cx1 * WW + cy0) : 0) * 16;
                pb_[it][2] = (v2 ? (cx0 * WW + cy1) : 0) * 16;
                pb_[it][3] = (v3 ? (cx1 * WW + cy1) : 0) * 16;
                fo_[it] = p * 128 + ((wv ^ (p & 7)) << 4);
            }
        }
    };

    // ---- fill chunk k: gather 8 ch of flow fi=wv from GLOBAL xt into fl[k&1] ----
    auto fill = [&](int k) {
        const char* xcb = xtb + (k & 7) * 6400;   // this chunk's 6.4KB plane (L1-hot)
        char* flb = (char*)fl[k & 1];
        #pragma unroll
        for (int it = 0; it < 2; ++it) {
            if (it == 0 || lane < PT - 64) {
                __half2 s0 = __builtin_bit_cast(__half2, 0u);
                __half2 s1 = s0, s2 = s0, s3 = s0;
                #pragma unroll
                for (int q = 0; q < 4; ++q) {
                    const uint4 d = *(const uint4*)(xcb + pb_[it][q]);   // global 16B
                    __half2 wq = w2_[it][q];
                    s0 = __hfma2(wq, __builtin_bit_cast(__half2, d.x), s0);
                    s1 = __hfma2(wq, __builtin_bit_cast(__half2, d.y), s1);
                    s2 = __hfma2(wq, __builtin_bit_cast(__half2, d.z), s2);
                    s3 = __hfma2(wq, __builtin_bit_cast(__half2, d.w), s3);
                }
                uint4 pk;
                pk.x = __builtin_bit_cast(uint32_t, s0);
                pk.y = __builtin_bit_cast(uint32_t, s1);
                pk.z = __builtin_bit_cast(uint32_t, s2);
                pk.w = __builtin_bit_cast(uint32_t, s3);
                *(uint4*)(flb + fo_[it]) = pk;    // swizzled cell, conflict-free
            }
        }
    };

    build_tables(0);
    fill(0);
    __syncthreads();   // fl[0] ready (no xb staging barrier anymore)

    f4 acc[2][NFR] = {};

    // B-read swizzle constants: row p = nf*16+lr -> p&7 == lr&7
    const int q0 = (hq ^ (lr & 7)) << 4;      // fi = hq cell; fi = hq+4 at ^64

    for (int kc = 0; kc < 16; ++kc) {          // chunk = (fb = kc>>3, cb = kc&7)
        if (kc == 7) build_tables(1);          // tables for fb=1 before fill(8)

        // ---- A-frags: 2 M-frags x 2 k-halves (L2-resident; fill covers latency) ----
        const sh8* wfp = (const sh8*)Wf + (size_t)(2 * kc * 16 + 2 * wv) * 64 + lane;
        sh8 a00 = wfp[0];          // kc16=2kc,   mf=2wv
        sh8 a01 = wfp[64];         // kc16=2kc,   mf=2wv+1
        sh8 a10 = wfp[1024];       // kc16=2kc+1, mf=2wv
        sh8 a11 = wfp[1088];       // kc16=2kc+1, mf=2wv+1

        // ---- fill next chunk into the other buffer (hazard cleared by the
        //      barrier at the end of the previous iteration) ----
        if (kc <= 14) fill(kc + 1);

        // ---- MFMA on current chunk: 28 x 16x16x32_f16 per wave ----
        const char* flr_b = (const char*)fl[kc & 1];
        __builtin_amdgcn_s_setprio(1);
        #pragma unroll
        for (int nf = 0; nf < NFR; ++nf) {
            int rowb = (nf * 16 + lr) * 128;
            sh8 b0 = *(const sh8*)(flr_b + (rowb + q0));
            acc[0][nf] = __builtin_amdgcn_mfma_f32_16x16x32_f16(a00, b0, acc[0][nf], 0, 0, 0);
            acc[1][nf] = __builtin_amdgcn_mfma_f32_16x16x32_f16(a01, b0, acc[1][nf], 0, 0, 0);
            sh8 b1 = *(const sh8*)(flr_b + ((rowb + q0) ^ 64));
            acc[0][nf] = __builtin_amdgcn_mfma_f32_16x16x32_f16(a10, b1, acc[0][nf], 0, 0, 0);
            acc[1][nf] = __builtin_amdgcn_mfma_f32_16x16x32_f16(a11, b1, acc[1][nf], 0, 0, 0);
        }
        __builtin_amdgcn_s_setprio(0);

        __syncthreads();   // fl[(kc+1)&1] complete for all waves (sole barrier)
    }

    // ---- epilogue: bias + fp32 store (guard cols >= 100) ----
    float* ob = outg + (size_t)b * (COUT * NPIX) + p0;
    #pragma unroll
    for (int mi = 0; mi < 2; ++mi) {
        #pragma unroll
        for (int r = 0; r < 4; ++r) {
            int m = (wv * 2 + mi) * 16 + hq * 4 + r;
            float bs = biasg[m];
            #pragma unroll
            for (int nf = 0; nf < NFR; ++nf) {
                if (nf < 6 || lr < 4)
                    ob[(size_t)m * NPIX + nf * 16 + lr] = acc[mi][nf][r] + bs;
            }
        }
    }
}

extern "C" void kernel_launch(void* const* d_in, const int* in_sizes, int n_in,
                              void* d_out, int out_size, void* d_ws, size_t ws_size,
                              hipStream_t stream) {
    const float* x    = (const float*)d_in[0];
    const float* flow = (const float*)d_in[1];
    const float* comb = (const float*)d_in[2];
    const float* bias = (const float*)d_in[3];
    float* out = (float*)d_out;

    __half* Wf = (__half*)d_ws;                          // 512 KB frag-layout f16 W
    __half* xt = (__half*)((char*)d_ws + (512 << 10));   // 6.55 MB f16 chunk-planar x

    prep_w<<<dim3(128), dim3(256), 0, stream>>>(comb, Wf);
    prep_x<<<dim3(1600), dim3(256), 0, stream>>>(x, xt);
    flow_main<<<dim3(BATCH * NPT), dim3(NTH), 0, stream>>>(xt, Wf, flow, bias, out);
}

// Round 12
// 56.527 us; speedup vs baseline: 1.0982x; 1.0982x over previous
//
#include <hip/hip_runtime.h>
#include <hip/hip_fp16.h>
#include <stdint.h>

#define BATCH 128
#define CIN   64
#define NFLOW 16
#define COUT  256
#define HH    20
#define WW    20
#define NPIX  400
#define KTOT  1024
#define PT    100         // pixel tile (5 image rows)
#define NPT   4           // tiles per batch -> 512 blocks = exactly 2/CU
#define NTH   512         // 8 waves, each owns 32 out-rows x all 7 N-frags
#define NFR   7           // N-frags per tile (112 cols cover 100 pixels)
#define FLR   112         // fl rows (NFR*16)

typedef __attribute__((ext_vector_type(8))) short sh8;   // MFMA A/B frag (8 f16)
typedef __attribute__((ext_vector_type(4))) float f4;    // MFMA C/D frag

// ---- prep: W fp32 [256][1024] -> f16 MFMA-frag layout over permuted k' ----
// k' = kc*64 + fi*8 + ci ; kc = fb*8 + cb ; f = fb*8+fi, c = cb*8+ci, k = c*16+f.
// Frag layout: Wf[((kc16*16 + mf)*64 + h*16 + lr)*8 + j], k' = kc16*32 + h*8 + j,
// row m = mf*16 + lr.
__global__ void prep_w(const float* __restrict__ wg, __half* __restrict__ Wf) {
    int gid = blockIdx.x * 256 + threadIdx.x;   // [0, 32768)
    int j8  = gid & 127;          // k'-octet 0..127
    int row = gid >> 7;           // 0..255
    int kc16 = j8 >> 2;
    int h    = j8 & 3;
    __half* dst = Wf + ((size_t)(kc16 * 16 + (row >> 4)) * 64 + h * 16 + (row & 15)) * 8;
    #pragma unroll
    for (int j = 0; j < 8; ++j) {
        int kp = j8 * 8 + j;                  // k' in [0,1024)
        int kc = kp >> 6;
        int l  = kp & 63;
        int f  = (kc >> 3) * 8 + (l >> 3);
        int c  = (kc & 7) * 8 + (l & 7);
        dst[j] = __float2half(wg[(size_t)row * KTOT + c * NFLOW + f]);
    }
}

__global__ __launch_bounds__(NTH, 4) void flow_main(
    const float* __restrict__ xg, const __half* __restrict__ Wf,
    const float* __restrict__ flowg, const float* __restrict__ biasg,
    float* __restrict__ outg)
{
    // xb: whole image, cell layout xb[(cb*400 + pix)*8 + ci] f16 (16 B cells)
    __shared__ __align__(16) __half xb[CIN * NPIX];       // 51200 B
    // fl: B-tile dbuf, row stride 64 f16 = 128 B, XOR-swizzled 16B cells
    __shared__ __align__(16) __half fl[2][FLR * 64];      // 28672 B  (total 79872 B)

    const int bid0 = blockIdx.x;
    const int bid  = (bid0 & 7) * 64 + (bid0 >> 3);       // XCD swizzle (512 % 8 == 0)
    const int b  = bid >> 2;
    const int pt = bid & 3;
    const int p0 = pt * PT;

    const int tid  = threadIdx.x;
    const int wv   = tid >> 6;        // wave owns out-rows [wv*32, wv*32+32), flow fi=wv
    const int lane = tid & 63;
    const int lr   = lane & 15;
    const int hq   = lane >> 4;       // k-slice quarter 0..3

    const float* xsrc = xg + (size_t)b * (CIN * NPIX);

    // ---- stage x once: f32 global -> f16 cells (b128 writes, stride-16B) ----
    #pragma unroll
    for (int it = 0; it < 7; ++it) {
        int idx = it * NTH + tid;              // cell id in [0, 3200)
        if (idx < 3200) {
            int cb  = idx / NPIX;
            int pix = idx - cb * NPIX;
            const float* s = xsrc + (size_t)(cb * 8) * NPIX + pix;
            __half2 h0 = __floats2half2_rn(s[0 * NPIX], s[1 * NPIX]);
            __half2 h1 = __floats2half2_rn(s[2 * NPIX], s[3 * NPIX]);
            __half2 h2 = __floats2half2_rn(s[4 * NPIX], s[5 * NPIX]);
            __half2 h3 = __floats2half2_rn(s[6 * NPIX], s[7 * NPIX]);
            uint4 pk;
            pk.x = __builtin_bit_cast(uint32_t, h0);
            pk.y = __builtin_bit_cast(uint32_t, h1);
            pk.z = __builtin_bit_cast(uint32_t, h2);
            pk.w = __builtin_bit_cast(uint32_t, h3);
            *(uint4*)&xb[(size_t)idx * 8] = pk;
        }
    }

    // ---- warp tables: wave wv handles flow fi=wv, pixels p = it*64 + lane ----
    __half2 w2_[2][4];
    int     pb_[2][4];     // corner cell byte offset within plane (r * 16)
    int     fo_[2];        // fl byte offset = p*128 + ((wv ^ (p&7))<<4)

    auto build_tables = [&](int fb) {
        #pragma unroll
        for (int it = 0; it < 2; ++it) {
            if (it == 0 || lane < PT - 64) {
                int p  = it * 64 + lane;       // [0,100)
                int f  = fb * 8 + wv;
                int gp = p0 + p;
                int i = gp / WW;
                int j = gp - i * WW;
                float fx = flowg[((f * HH + i) * WW + j) * 2 + 0];
                float fy = flowg[((f * HH + i) * WW + j) * 2 + 1];
                float ax = (float)i + fx;
                float ay = (float)j + fy;
                float bxf = floorf(ax), byf = floorf(ay);
                float s = ax - bxf, t = ay - byf;
                int ibx = (int)bxf, iby = (int)byf;
                float w00 = (1.f - s) * (1.f - t);
                float w01 = s * (1.f - t);
                float w10 = s * (1.f - t);        // replicate reference's weight bug
                float w11 = s * t;
                int cx0 = min(max(ibx, 0), HH);
                int cx1 = min(max(ibx + 1, 0), HH);
                int cy0 = min(max(iby, 0), WW);
                int cy1 = min(max(iby + 1, 0), WW);
                int v0 = (cx0 < HH) & (cy0 < WW);
                int v1 = (cx1 < HH) & (cy0 < WW);
                int v2 = (cx0 < HH) & (cy1 < WW);
                int v3 = (cx1 < HH) & (cy1 < WW);
                w2_[it][0] = __half2half2(__float2half(v0 ? w00 : 0.f));
                w2_[it][1] = __half2half2(__float2half(v1 ? w01 : 0.f));
                w2_[it][2] = __half2half2(__float2half(v2 ? w10 : 0.f));
                w2_[it][3] = __half2half2(__float2half(v3 ? w11 : 0.f));
                pb_[it][0] = (v0 ? (cx0 * WW + cy0) : 0) * 16;
                pb_[it][1] = (v1 ? (cx1 * WW + cy0) : 0) * 16;
                pb_[it][2] = (v2 ? (cx0 * WW + cy1) : 0) * 16;
                pb_[it][3] = (v3 ? (cx1 * WW + cy1) : 0) * 16;
                fo_[it] = p * 128 + ((wv ^ (p & 7)) << 4);
            }
        }
    };

    // ---- fill chunk k: all 8 gathers first, then math, then 2 writes ----
    auto fill = [&](int k) {
        const char* xcb = (const char*)xb + (k & 7) * 6400;
        char* flb = (char*)fl[k & 1];
        uint4 d[2][4];
        #pragma unroll
        for (int it = 0; it < 2; ++it) {
            if (it == 0 || lane < PT - 64) {
                #pragma unroll
                for (int q = 0; q < 4; ++q)
                    d[it][q] = *(const uint4*)(xcb + pb_[it][q]);
            }
        }
        #pragma unroll
        for (int it = 0; it < 2; ++it) {
            if (it == 0 || lane < PT - 64) {
                __half2 s0 = __builtin_bit_cast(__half2, 0u);
                __half2 s1 = s0, s2 = s0, s3 = s0;
                #pragma unroll
                for (int q = 0; q < 4; ++q) {
                    __half2 wq = w2_[it][q];
                    s0 = __hfma2(wq, __builtin_bit_cast(__half2, d[it][q].x), s0);
                    s1 = __hfma2(wq, __builtin_bit_cast(__half2, d[it][q].y), s1);
                    s2 = __hfma2(wq, __builtin_bit_cast(__half2, d[it][q].z), s2);
                    s3 = __hfma2(wq, __builtin_bit_cast(__half2, d[it][q].w), s3);
                }
                uint4 pk;
                pk.x = __builtin_bit_cast(uint32_t, s0);
                pk.y = __builtin_bit_cast(uint32_t, s1);
                pk.z = __builtin_bit_cast(uint32_t, s2);
                pk.w = __builtin_bit_cast(uint32_t, s3);
                *(uint4*)(flb + fo_[it]) = pk;    // swizzled cell, conflict-free
            }
        }
    };

    build_tables(0);
    __syncthreads();   // xb staged
    fill(0);
    __syncthreads();   // fl[0] ready

    f4 acc[2][NFR] = {};

    // B-read swizzle constants: row p = nf*16+lr -> p&7 == lr&7
    const int q0 = (hq ^ (lr & 7)) << 4;      // fi = hq cell; fi = hq+4 at ^64

    for (int kc = 0; kc < 16; ++kc) {          // chunk = (fb = kc>>3, cb = kc&7)
        if (kc == 7) build_tables(1);          // tables for fb=1 before fill(8)

        // ---- A-frags: 2 M-frags x 2 k-halves (L2-resident; fill covers latency) ----
        const sh8* wfp = (const sh8*)Wf + (size_t)(2 * kc * 16 + 2 * wv) * 64 + lane;
        sh8 a00 = wfp[0];          // kc16=2kc,   mf=2wv
        sh8 a01 = wfp[64];         // kc16=2kc,   mf=2wv+1
        sh8 a10 = wfp[1024];       // kc16=2kc+1, mf=2wv
        sh8 a11 = wfp[1088];       // kc16=2kc+1, mf=2wv+1

        // ---- prefetch nf=0 B-pair from the buffer filled last iteration
        //      (post-barrier: safe; issued before fill's DS ops, completes first) ----
        const char* flr_b = (const char*)fl[kc & 1];
        sh8 b0 = *(const sh8*)(flr_b + (lr * 128 + q0));
        sh8 b1 = *(const sh8*)(flr_b + ((lr * 128 + q0) ^ 64));

        // ---- fill next chunk into the other buffer ----
        if (kc <= 14) fill(kc + 1);

        // ---- MFMA: rolling B-prefetch one N-frag ahead ----
        __builtin_amdgcn_s_setprio(1);
        #pragma unroll
        for (int nf = 0; nf < NFR; ++nf) {
            sh8 c0 = b0, c1 = b1;
            if (nf + 1 < NFR) {
                int rb = ((nf + 1) * 16 + lr) * 128;
                b0 = *(const sh8*)(flr_b + (rb + q0));
                b1 = *(const sh8*)(flr_b + ((rb + q0) ^ 64));
            }
            acc[0][nf] = __builtin_amdgcn_mfma_f32_16x16x32_f16(a00, c0, acc[0][nf], 0, 0, 0);
            acc[1][nf] = __builtin_amdgcn_mfma_f32_16x16x32_f16(a01, c0, acc[1][nf], 0, 0, 0);
            acc[0][nf] = __builtin_amdgcn_mfma_f32_16x16x32_f16(a10, c1, acc[0][nf], 0, 0, 0);
            acc[1][nf] = __builtin_amdgcn_mfma_f32_16x16x32_f16(a11, c1, acc[1][nf], 0, 0, 0);
        }
        __builtin_amdgcn_s_setprio(0);

        __syncthreads();   // fl[(kc+1)&1] complete for all waves (sole barrier)
    }

    // ---- epilogue: bias + fp32 store (guard cols >= 100) ----
    float* ob = outg + (size_t)b * (COUT * NPIX) + p0;
    #pragma unroll
    for (int mi = 0; mi < 2; ++mi) {
        #pragma unroll
        for (int r = 0; r < 4; ++r) {
            int m = (wv * 2 + mi) * 16 + hq * 4 + r;
            float bs = biasg[m];
            #pragma unroll
            for (int nf = 0; nf < NFR; ++nf) {
                if (nf < 6 || lr < 4)
                    ob[(size_t)m * NPIX + nf * 16 + lr] = acc[mi][nf][r] + bs;
            }
        }
    }
}

extern "C" void kernel_launch(void* const* d_in, const int* in_sizes, int n_in,
                              void* d_out, int out_size, void* d_ws, size_t ws_size,
                              hipStream_t stream) {
    const float* x    = (const float*)d_in[0];
    const float* flow = (const float*)d_in[1];
    const float* comb = (const float*)d_in[2];
    const float* bias = (const float*)d_in[3];
    float* out = (float*)d_out;

    __half* Wf = (__half*)d_ws;   // 512 KB frag-layout f16 W

    prep_w<<<dim3(128), dim3(256), 0, stream>>>(comb, Wf);
    flow_main<<<dim3(BATCH * NPT), dim3(NTH), 0, stream>>>(x, Wf, flow, bias, out);
}

// Round 13
// 48.336 us; speedup vs baseline: 1.2843x; 1.1695x over previous
//
#include <hip/hip_runtime.h>
#include <hip/hip_fp16.h>
#include <stdint.h>

#define BATCH 128
#define CIN   64
#define NFLOW 16
#define COUT  256
#define HH    20
#define WW    20
#define NPIX  400
#define KTOT  1024
#define PT    100         // pixel tile (5 image rows)
#define NPT   4           // tiles per batch -> 512 blocks = exactly 2/CU
#define NTH   512         // 8 waves, each owns 32 out-rows x all 7 N-frags
#define NFR   7           // N-frags per tile (112 cols cover 100 pixels)
#define FLR   112         // fl rows (NFR*16)

typedef __attribute__((ext_vector_type(8))) short sh8;   // MFMA A/B frag (8 f16)
typedef __attribute__((ext_vector_type(4))) float f4;    // MFMA C/D frag

// ---- prep: W fp32 [256][1024] -> f16 MFMA-frag layout over permuted k' ----
// k' = kc*64 + fi*8 + ci ; kc = fb*8 + cb ; f = fb*8+fi, c = cb*8+ci, k = c*16+f.
// Frag layout: Wf[((kc16*16 + mf)*64 + h*16 + lr)*8 + j], k' = kc16*32 + h*8 + j,
// row m = mf*16 + lr.
__global__ void prep_w(const float* __restrict__ wg, __half* __restrict__ Wf) {
    int gid = blockIdx.x * 256 + threadIdx.x;   // [0, 32768)
    int j8  = gid & 127;          // k'-octet 0..127
    int row = gid >> 7;           // 0..255
    int kc16 = j8 >> 2;
    int h    = j8 & 3;
    __half* dst = Wf + ((size_t)(kc16 * 16 + (row >> 4)) * 64 + h * 16 + (row & 15)) * 8;
    #pragma unroll
    for (int j = 0; j < 8; ++j) {
        int kp = j8 * 8 + j;                  // k' in [0,1024)
        int kc = kp >> 6;
        int l  = kp & 63;
        int f  = (kc >> 3) * 8 + (l >> 3);
        int c  = (kc & 7) * 8 + (l & 7);
        dst[j] = __float2half(wg[(size_t)row * KTOT + c * NFLOW + f]);
    }
}

__global__ __launch_bounds__(NTH, 4) void flow_main(
    const float* __restrict__ xg, const __half* __restrict__ Wf,
    const float* __restrict__ flowg, const float* __restrict__ biasg,
    float* __restrict__ outg)
{
    // xb: whole image, cell layout xb[(cb*400 + pix)*8 + ci] f16 (16 B cells)
    __shared__ __align__(16) __half xb[CIN * NPIX];       // 51200 B
    // fl: B-tile dbuf, row stride 64 f16 = 128 B, XOR-swizzled 16B cells
    __shared__ __align__(16) __half fl[2][FLR * 64];      // 28672 B  (total 79872 B)

    const int bid0 = blockIdx.x;
    const int bid  = (bid0 & 7) * 64 + (bid0 >> 3);       // XCD swizzle (512 % 8 == 0)
    const int b  = bid >> 2;
    const int pt = bid & 3;
    const int p0 = pt * PT;

    const int tid  = threadIdx.x;
    const int wv   = tid >> 6;        // wave owns out-rows [wv*32, wv*32+32), flow fi=wv
    const int lane = tid & 63;
    const int lr   = lane & 15;
    const int hq   = lane >> 4;       // k-slice quarter 0..3

    const float* xsrc = xg + (size_t)b * (CIN * NPIX);

    // ---- stage x once: f32 global -> f16 cells (b128 writes, stride-16B) ----
    #pragma unroll
    for (int it = 0; it < 7; ++it) {
        int idx = it * NTH + tid;              // cell id in [0, 3200)
        if (idx < 3200) {
            int cb  = idx / NPIX;
            int pix = idx - cb * NPIX;
            const float* s = xsrc + (size_t)(cb * 8) * NPIX + pix;
            __half2 h0 = __floats2half2_rn(s[0 * NPIX], s[1 * NPIX]);
            __half2 h1 = __floats2half2_rn(s[2 * NPIX], s[3 * NPIX]);
            __half2 h2 = __floats2half2_rn(s[4 * NPIX], s[5 * NPIX]);
            __half2 h3 = __floats2half2_rn(s[6 * NPIX], s[7 * NPIX]);
            uint4 pk;
            pk.x = __builtin_bit_cast(uint32_t, h0);
            pk.y = __builtin_bit_cast(uint32_t, h1);
            pk.z = __builtin_bit_cast(uint32_t, h2);
            pk.w = __builtin_bit_cast(uint32_t, h3);
            *(uint4*)&xb[(size_t)idx * 8] = pk;
        }
    }

    // ---- warp tables: wave wv handles flow fi=wv, pixels p = it*64 + lane ----
    __half2 w2_[2][4];
    int     pb_[2][4];     // corner cell byte offset within plane (r * 16)
    int     fo_[2];        // fl byte offset = p*128 + ((wv ^ (p&7))<<4)

    auto build_tables = [&](int fb) {
        #pragma unroll
        for (int it = 0; it < 2; ++it) {
            if (it == 0 || lane < PT - 64) {
                int p  = it * 64 + lane;       // [0,100)
                int f  = fb * 8 + wv;
                int gp = p0 + p;
                int i = gp / WW;
                int j = gp - i * WW;
                float fx = flowg[((f * HH + i) * WW + j) * 2 + 0];
                float fy = flowg[((f * HH + i) * WW + j) * 2 + 1];
                float ax = (float)i + fx;
                float ay = (float)j + fy;
                float bxf = floorf(ax), byf = floorf(ay);
                float s = ax - bxf, t = ay - byf;
                int ibx = (int)bxf, iby = (int)byf;
                float w00 = (1.f - s) * (1.f - t);
                float w01 = s * (1.f - t);
                float w10 = s * (1.f - t);        // replicate reference's weight bug
                float w11 = s * t;
                int cx0 = min(max(ibx, 0), HH);
                int cx1 = min(max(ibx + 1, 0), HH);
                int cy0 = min(max(iby, 0), WW);
                int cy1 = min(max(iby + 1, 0), WW);
                int v0 = (cx0 < HH) & (cy0 < WW);
                int v1 = (cx1 < HH) & (cy0 < WW);
                int v2 = (cx0 < HH) & (cy1 < WW);
                int v3 = (cx1 < HH) & (cy1 < WW);
                w2_[it][0] = __half2half2(__float2half(v0 ? w00 : 0.f));
                w2_[it][1] = __half2half2(__float2half(v1 ? w01 : 0.f));
                w2_[it][2] = __half2half2(__float2half(v2 ? w10 : 0.f));
                w2_[it][3] = __half2half2(__float2half(v3 ? w11 : 0.f));
                pb_[it][0] = (v0 ? (cx0 * WW + cy0) : 0) * 16;
                pb_[it][1] = (v1 ? (cx1 * WW + cy0) : 0) * 16;
                pb_[it][2] = (v2 ? (cx0 * WW + cy1) : 0) * 16;
                pb_[it][3] = (v3 ? (cx1 * WW + cy1) : 0) * 16;
                fo_[it] = p * 128 + ((wv ^ (p & 7)) << 4);
            }
        }
    };

    // ---- fill chunk k: gather 8 channels of flow fi=wv into fl[k&1] (R7 form) ----
    auto fill = [&](int k) {
        const char* xcb = (const char*)xb + (k & 7) * 6400;
        char* flb = (char*)fl[k & 1];
        #pragma unroll
        for (int it = 0; it < 2; ++it) {
            if (it == 0 || lane < PT - 64) {
                __half2 s0 = __builtin_bit_cast(__half2, 0u);
                __half2 s1 = s0, s2 = s0, s3 = s0;
                #pragma unroll
                for (int q = 0; q < 4; ++q) {
                    const uint4 d = *(const uint4*)(xcb + pb_[it][q]);
                    __half2 wq = w2_[it][q];
                    s0 = __hfma2(wq, __builtin_bit_cast(__half2, d.x), s0);
                    s1 = __hfma2(wq, __builtin_bit_cast(__half2, d.y), s1);
                    s2 = __hfma2(wq, __builtin_bit_cast(__half2, d.z), s2);
                    s3 = __hfma2(wq, __builtin_bit_cast(__half2, d.w), s3);
                }
                uint4 pk;
                pk.x = __builtin_bit_cast(uint32_t, s0);
                pk.y = __builtin_bit_cast(uint32_t, s1);
                pk.z = __builtin_bit_cast(uint32_t, s2);
                pk.w = __builtin_bit_cast(uint32_t, s3);
                *(uint4*)(flb + fo_[it]) = pk;    // swizzled cell, conflict-free
            }
        }
    };

    build_tables(0);
    __syncthreads();   // xb staged
    fill(0);
    __syncthreads();   // fl[0] ready

    f4 acc[2][NFR] = {};

    // B-read swizzle constants: row p = nf*16+lr -> p&7 == lr&7
    const int q0 = (hq ^ (lr & 7)) << 4;      // fi = hq cell; fi = hq+4 at ^64

    for (int kc = 0; kc < 16; ++kc) {          // chunk = (fb = kc>>3, cb = kc&7)
        if (kc == 7) build_tables(1);          // tables for fb=1 before fill(8)

        // ---- A-frags first (longest latency, global/L2) ----
        const sh8* wfp = (const sh8*)Wf + (size_t)(2 * kc * 16 + 2 * wv) * 64 + lane;
        sh8 a00 = wfp[0];          // kc16=2kc,   mf=2wv
        sh8 a01 = wfp[64];         // kc16=2kc,   mf=2wv+1
        sh8 a10 = wfp[1024];       // kc16=2kc+1, mf=2wv
        sh8 a11 = wfp[1088];       // kc16=2kc+1, mf=2wv+1

        // ---- prefetch nf=0 B-pair (post-barrier: reads last iteration's fill) ----
        const char* flr_b = (const char*)fl[kc & 1];
        sh8 b0 = *(const sh8*)(flr_b + (lr * 128 + q0));
        sh8 b1 = *(const sh8*)(flr_b + ((lr * 128 + q0) ^ 64));

        // ---- fill next chunk into the other buffer ----
        if (kc <= 14) fill(kc + 1);

        // ---- MFMA: rolling B-prefetch one N-frag ahead ----
        __builtin_amdgcn_s_setprio(1);
        #pragma unroll
        for (int nf = 0; nf < NFR; ++nf) {
            sh8 c0 = b0, c1 = b1;
            if (nf + 1 < NFR) {
                int rb = ((nf + 1) * 16 + lr) * 128;
                b0 = *(const sh8*)(flr_b + (rb + q0));
                b1 = *(const sh8*)(flr_b + ((rb + q0) ^ 64));
            }
            acc[0][nf] = __builtin_amdgcn_mfma_f32_16x16x32_f16(a00, c0, acc[0][nf], 0, 0, 0);
            acc[1][nf] = __builtin_amdgcn_mfma_f32_16x16x32_f16(a01, c0, acc[1][nf], 0, 0, 0);
            acc[0][nf] = __builtin_amdgcn_mfma_f32_16x16x32_f16(a10, c1, acc[0][nf], 0, 0, 0);
            acc[1][nf] = __builtin_amdgcn_mfma_f32_16x16x32_f16(a11, c1, acc[1][nf], 0, 0, 0);
        }
        __builtin_amdgcn_s_setprio(0);

        __syncthreads();   // fl[(kc+1)&1] complete for all waves (sole barrier)
    }

    // ---- epilogue: bias + fp32 store (guard cols >= 100) ----
    float* ob = outg + (size_t)b * (COUT * NPIX) + p0;
    #pragma unroll
    for (int mi = 0; mi < 2; ++mi) {
        #pragma unroll
        for (int r = 0; r < 4; ++r) {
            int m = (wv * 2 + mi) * 16 + hq * 4 + r;
            float bs = biasg[m];
            #pragma unroll
            for (int nf = 0; nf < NFR; ++nf) {
                if (nf < 6 || lr < 4)
                    ob[(size_t)m * NPIX + nf * 16 + lr] = acc[mi][nf][r] + bs;
            }
        }
    }
}

extern "C" void kernel_launch(void* const* d_in, const int* in_sizes, int n_in,
                              void* d_out, int out_size, void* d_ws, size_t ws_size,
                              hipStream_t stream) {
    const float* x    = (const float*)d_in[0];
    const float* flow = (const float*)d_in[1];
    const float* comb = (const float*)d_in[2];
    const float* bias = (const float*)d_in[3];
    float* out = (float*)d_out;

    __half* Wf = (__half*)d_ws;   // 512 KB frag-layout f16 W

    prep_w<<<dim3(128), dim3(256), 0, stream>>>(comb, Wf);
    flow_main<<<dim3(BATCH * NPT), dim3(NTH), 0, stream>>>(x, Wf, flow, bias, out);
}